// Round 2
// baseline (58.573 us; speedup 1.0000x reference)
//
#include <hip/hip_runtime.h>

#define K_Q   131072
#define B_N   1024
#define D_DIM 128
#define NCLS  10
#define CHUNKS 16
#define NEG_INF_F (-1e9f)

// ---------------- kernel 0: zero the atomic counters ----------------
__global__ void k_init(int* cnt, int* accCnt) {
    int t = threadIdx.x;
    if (t < 2 * NCLS) cnt[t] = 0;
    if (t == 0) *accCnt = 0;
}

// ---------------- kernel 1: per-k class code + class counts ----------------
// code[k] = qp[k]            if qp[k]==ql[k]  (correct -> pos candidate)
//         = qp[k] + NCLS     otherwise        (incorrect -> neg candidate)
__global__ void k_code(const int* __restrict__ qp, const int* __restrict__ ql,
                       unsigned char* __restrict__ code, int* __restrict__ cnt) {
    __shared__ int lc[2 * NCLS];
    int t = threadIdx.x;
    if (t < 2 * NCLS) lc[t] = 0;
    __syncthreads();
    int idx = blockIdx.x * blockDim.x + t;
    int stride = gridDim.x * blockDim.x;
    for (int k = idx; k < K_Q; k += stride) {
        int p = qp[k];
        int cd = (p == ql[k]) ? p : (p + NCLS);
        code[k] = (unsigned char)cd;
        atomicAdd(&lc[cd], 1);
    }
    __syncthreads();
    if (t < 2 * NCLS) atomicAdd(&cnt[t], lc[t]);
}

// ---------------- kernel 2: per-class column sums of both queues ----------------
__device__ __forceinline__ void acc_elem(int cdv, float pvx, float nvx,
                                         float* accp, float* accn) {
#pragma unroll
    for (int c = 0; c < NCLS; ++c) {
        accp[c] += (cdv == c)        ? pvx : 0.0f;
        accn[c] += (cdv == c + NCLS) ? nvx : 0.0f;
    }
}

__global__ __launch_bounds__(256, 8)
void k_reduce(const float* __restrict__ posq, const float* __restrict__ negq,
              const unsigned char* __restrict__ code,
              float* __restrict__ partial) {
    const int d  = blockIdx.y;
    const int ch = blockIdx.x;
    const int t  = threadIdx.x;      // 256 threads
    const int span = K_Q / CHUNKS;   // 8192
    const int k0 = ch * span;

    const float4* prow = (const float4*)(posq + (size_t)d * K_Q + k0);
    const float4* nrow = (const float4*)(negq + (size_t)d * K_Q + k0);
    const uchar4* crow = (const uchar4*)(code + k0);

    float accp[NCLS], accn[NCLS];
#pragma unroll
    for (int c = 0; c < NCLS; ++c) { accp[c] = 0.0f; accn[c] = 0.0f; }

    const int iters = span / 4 / 256;  // 8
#pragma unroll 4
    for (int it = 0; it < iters; ++it) {
        int i = it * 256 + t;
        float4 pv = prow[i];
        float4 nv = nrow[i];
        uchar4 cd = crow[i];
        acc_elem((int)cd.x, pv.x, nv.x, accp, accn);
        acc_elem((int)cd.y, pv.y, nv.y, accp, accn);
        acc_elem((int)cd.z, pv.z, nv.z, accp, accn);
        acc_elem((int)cd.w, pv.w, nv.w, accp, accn);
    }

    // wave-64 butterfly reduce all 20 accumulators
#pragma unroll
    for (int c = 0; c < NCLS; ++c) {
#pragma unroll
        for (int off = 32; off; off >>= 1) {
            accp[c] += __shfl_xor(accp[c], off);
            accn[c] += __shfl_xor(accn[c], off);
        }
    }

    __shared__ float wsum[4][2 * NCLS];
    int wave = t >> 6;
    if ((t & 63) == 0) {
#pragma unroll
        for (int c = 0; c < NCLS; ++c) {
            wsum[wave][c]        = accp[c];
            wsum[wave][c + NCLS] = accn[c];
        }
    }
    __syncthreads();
    if (t < 2 * NCLS) {
        float s = wsum[0][t] + wsum[1][t] + wsum[2][t] + wsum[3][t];
        partial[((size_t)d * CHUNKS + ch) * (2 * NCLS) + t] = s;
    }
}

// ---------------- kernel 3: sum chunk partials -> S[20][128] ----------------
__global__ void k_finalize(const float* __restrict__ partial, float* __restrict__ S) {
    int t = blockIdx.x * blockDim.x + threadIdx.x;  // 0..2559
    if (t >= D_DIM * 2 * NCLS) return;
    int d = t / (2 * NCLS);
    int j = t % (2 * NCLS);
    float s = 0.0f;
#pragma unroll
    for (int ch = 0; ch < CHUNKS; ++ch)
        s += partial[((size_t)d * CHUNKS + ch) * (2 * NCLS) + j];
    S[j * D_DIM + d] = s;   // j<10: pos class j; j>=10: neg class j-10
}

// ---------------- kernel 4: per-sample loss ----------------
__global__ void k_loss(const float* __restrict__ q, const int* __restrict__ preds,
                       const float* __restrict__ S, const int* __restrict__ cnt,
                       float* __restrict__ out, int* __restrict__ accCnt) {
    const int b = blockIdx.x;
    const int t = threadIdx.x;  // 128 threads
    const int c = preds[b];

    float qv = q[(size_t)b * D_DIM + t];
    float sp = S[c * D_DIM + t];
    float sn = S[(NCLS + c) * D_DIM + t];
    float s0 = qv * qv, s1 = qv * sp, s2 = qv * sn;

#pragma unroll
    for (int off = 32; off; off >>= 1) {
        s0 += __shfl_xor(s0, off);
        s1 += __shfl_xor(s1, off);
        s2 += __shfl_xor(s2, off);
    }
    __shared__ float red[2][3];
    int wave = t >> 6;
    if ((t & 63) == 0) { red[wave][0] = s0; red[wave][1] = s1; red[wave][2] = s2; }
    __syncthreads();
    if (t == 0) {
        float nq  = red[0][0] + red[1][0];
        float dp  = red[0][1] + red[1][1];
        float dn  = red[0][2] + red[1][2];
        float inv = 1.0f / fmaxf(sqrtf(nq), 1e-12f);
        int cp = cnt[c], cn = cnt[NCLS + c];
        float pl = (cp > 0) ? (dp * inv) / (float)(cp > 1 ? cp : 1) : NEG_INF_F;
        float nl = (cn > 0) ? (dn * inv) / (float)(cn > 1 ? cn : 1) : NEG_INF_F;
        float a  = pl / 0.07f;
        float bb = nl / 0.07f;
        float m  = fmaxf(a, bb);
        float loss = m + logf(expf(a - m) + expf(bb - m)) - a;
        out[b] = loss;
        if (a >= bb) atomicAdd(accCnt, 1);  // argmax ties -> index 0
    }
}

// ---------------- kernel 5: accuracy scalar ----------------
__global__ void k_acc(const int* __restrict__ accCnt, float* __restrict__ out) {
    out[B_N] = (float)(*accCnt) * (1.0f / (float)B_N);
}

extern "C" void kernel_launch(void* const* d_in, const int* in_sizes, int n_in,
                              void* d_out, int out_size, void* d_ws, size_t ws_size,
                              hipStream_t stream) {
    const float* q      = (const float*)d_in[0];
    // d_in[1] = k (unused downstream in reference)
    // d_in[2] = labels (unused downstream)
    const int* preds    = (const int*)d_in[3];
    const float* posq   = (const float*)d_in[4];
    const float* negq   = (const float*)d_in[5];
    const int* qlabels  = (const int*)d_in[6];
    const int* qpreds   = (const int*)d_in[7];
    float* out = (float*)d_out;

    char* ws = (char*)d_ws;
    unsigned char* code = (unsigned char*)ws;               // 131072 B
    int* cnt            = (int*)(ws + 131072);              // 20 ints
    int* accCnt         = (int*)(ws + 131072 + 80);         // 1 int
    float* partial      = (float*)(ws + 131168);            // D*CHUNKS*20 floats
    float* S            = (float*)(ws + 131168 + D_DIM * CHUNKS * 2 * NCLS * 4);

    k_init<<<1, 64, 0, stream>>>(cnt, accCnt);
    k_code<<<256, 256, 0, stream>>>(qpreds, qlabels, code, cnt);
    k_reduce<<<dim3(CHUNKS, D_DIM), 256, 0, stream>>>(posq, negq, code, partial);
    k_finalize<<<10, 256, 0, stream>>>(partial, S);
    k_loss<<<B_N, 128, 0, stream>>>(q, preds, S, cnt, out, accCnt);
    k_acc<<<1, 1, 0, stream>>>(accCnt, out);
}

// Round 3
// 47.623 us; speedup vs baseline: 1.2299x; 1.2299x over previous
//
#include <hip/hip_runtime.h>

#define K_Q   131072
#define B_N   1024
#define D_DIM 128
#define NCLS  10
#define NC2   (2 * NCLS)      // 20
#define CHUNKS 16
#define NEG_INF_F (-1e9f)

// ---------------- kernel 0: zero the atomic counters ----------------
__global__ void k_init(int* cnt, int* accCnt) {
    int t = threadIdx.x;
    if (t < NC2) cnt[t] = 0;
    if (t == 0) *accCnt = 0;
}

// ---------------- kernel 1: per-k class code + class counts ----------------
__global__ void k_code(const int* __restrict__ qp, const int* __restrict__ ql,
                       unsigned char* __restrict__ code, int* __restrict__ cnt) {
    __shared__ int lc[NC2];
    int t = threadIdx.x;
    if (t < NC2) lc[t] = 0;
    __syncthreads();
    int idx = blockIdx.x * blockDim.x + t;
    int stride = gridDim.x * blockDim.x;
    for (int k = idx; k < K_Q; k += stride) {
        int p = qp[k];
        int cd = (p == ql[k]) ? p : (p + NCLS);
        code[k] = (unsigned char)cd;
        atomicAdd(&lc[cd], 1);
    }
    __syncthreads();
    if (t < NC2) atomicAdd(&cnt[t], lc[t]);
}

// ---------------- kernel 2: per-class column sums, LDS-indexed accumulators ----
__global__ __launch_bounds__(256, 4)
void k_reduce(const float* __restrict__ posq, const float* __restrict__ negq,
              const unsigned char* __restrict__ code,
              float* __restrict__ partial) {
    __shared__ float acc[256 * NC2];   // 20 KB: per-thread 20-slot accumulator
    const int d  = blockIdx.y;
    const int ch = blockIdx.x;
    const int t  = threadIdx.x;        // 256 threads
    const int span = K_Q / CHUNKS;     // 8192
    const int k0 = ch * span;

    // zero my accumulator slots
    float* my = &acc[t * NC2];
#pragma unroll
    for (int j = 0; j < NC2; ++j) my[j] = 0.0f;
    __syncthreads();

    const float4* prow = (const float4*)(posq + (size_t)d * K_Q + k0);
    const float4* nrow = (const float4*)(negq + (size_t)d * K_Q + k0);
    const uchar4* crow = (const uchar4*)(code + k0);

    const int iters = span / 4 / 256;  // 8

    // software pipeline: preload iter 0
    float4 pv = prow[t];
    float4 nv = nrow[t];
    uchar4 cd = crow[t];

    for (int it = 0; it < iters; ++it) {
        float4 cpv = pv, cnv = nv;
        uchar4 ccd = cd;
        int nx = (it + 1) * 256 + t;
        if (it + 1 < iters) {           // prefetch next iter before compute
            pv = prow[nx];
            nv = nrow[nx];
            cd = crow[nx];
        }
        {
            int c0 = ccd.x; my[c0] += (c0 < NCLS) ? cpv.x : cnv.x;
            int c1 = ccd.y; my[c1] += (c1 < NCLS) ? cpv.y : cnv.y;
            int c2 = ccd.z; my[c2] += (c2 < NCLS) ? cpv.z : cnv.z;
            int c3 = ccd.w; my[c3] += (c3 < NCLS) ? cpv.w : cnv.w;
        }
    }
    __syncthreads();

    // fold 256 -> 64 thread-rows
    if (t < 128) {
#pragma unroll
        for (int j = 0; j < NC2; ++j) acc[t * NC2 + j] += acc[(t + 128) * NC2 + j];
    }
    __syncthreads();
    if (t < 64) {
#pragma unroll
        for (int j = 0; j < NC2; ++j) acc[t * NC2 + j] += acc[(t + 64) * NC2 + j];
    }
    __syncthreads();

    // wave 0: butterfly-reduce the 64 remaining rows
    if (t < 64) {
        float r[NC2];
#pragma unroll
        for (int j = 0; j < NC2; ++j) {
            float x = acc[t * NC2 + j];
#pragma unroll
            for (int off = 32; off; off >>= 1) x += __shfl_xor(x, off);
            r[j] = x;
        }
        if (t == 0) {
#pragma unroll
            for (int j = 0; j < NC2; ++j)
                partial[((size_t)d * CHUNKS + ch) * NC2 + j] = r[j];
        }
    }
}

// ---------------- kernel 3: sum chunk partials -> S[20][128] ----------------
__global__ void k_finalize(const float* __restrict__ partial, float* __restrict__ S) {
    int t = blockIdx.x * blockDim.x + threadIdx.x;  // 0..2559
    if (t >= D_DIM * NC2) return;
    int d = t / NC2;
    int j = t % NC2;
    float s = 0.0f;
#pragma unroll
    for (int ch = 0; ch < CHUNKS; ++ch)
        s += partial[((size_t)d * CHUNKS + ch) * NC2 + j];
    S[j * D_DIM + d] = s;   // j<10: pos class j; j>=10: neg class j-10
}

// ---------------- kernel 4: per-sample loss ----------------
__global__ void k_loss(const float* __restrict__ q, const int* __restrict__ preds,
                       const float* __restrict__ S, const int* __restrict__ cnt,
                       float* __restrict__ out, int* __restrict__ accCnt) {
    const int b = blockIdx.x;
    const int t = threadIdx.x;  // 128 threads
    const int c = preds[b];

    float qv = q[(size_t)b * D_DIM + t];
    float sp = S[c * D_DIM + t];
    float sn = S[(NCLS + c) * D_DIM + t];
    float s0 = qv * qv, s1 = qv * sp, s2 = qv * sn;

#pragma unroll
    for (int off = 32; off; off >>= 1) {
        s0 += __shfl_xor(s0, off);
        s1 += __shfl_xor(s1, off);
        s2 += __shfl_xor(s2, off);
    }
    __shared__ float red[2][3];
    int wave = t >> 6;
    if ((t & 63) == 0) { red[wave][0] = s0; red[wave][1] = s1; red[wave][2] = s2; }
    __syncthreads();
    if (t == 0) {
        float nq  = red[0][0] + red[1][0];
        float dp  = red[0][1] + red[1][1];
        float dn  = red[0][2] + red[1][2];
        float inv = 1.0f / fmaxf(sqrtf(nq), 1e-12f);
        int cp = cnt[c], cn = cnt[NCLS + c];
        float pl = (cp > 0) ? (dp * inv) / (float)(cp > 1 ? cp : 1) : NEG_INF_F;
        float nl = (cn > 0) ? (dn * inv) / (float)(cn > 1 ? cn : 1) : NEG_INF_F;
        float a  = pl / 0.07f;
        float bb = nl / 0.07f;
        float m  = fmaxf(a, bb);
        float loss = m + logf(expf(a - m) + expf(bb - m)) - a;
        out[b] = loss;
        if (a >= bb) atomicAdd(accCnt, 1);  // argmax ties -> index 0
    }
}

// ---------------- kernel 5: accuracy scalar ----------------
__global__ void k_acc(const int* __restrict__ accCnt, float* __restrict__ out) {
    out[B_N] = (float)(*accCnt) * (1.0f / (float)B_N);
}

extern "C" void kernel_launch(void* const* d_in, const int* in_sizes, int n_in,
                              void* d_out, int out_size, void* d_ws, size_t ws_size,
                              hipStream_t stream) {
    const float* q      = (const float*)d_in[0];
    // d_in[1] = k (unused downstream in reference)
    // d_in[2] = labels (unused downstream)
    const int* preds    = (const int*)d_in[3];
    const float* posq   = (const float*)d_in[4];
    const float* negq   = (const float*)d_in[5];
    const int* qlabels  = (const int*)d_in[6];
    const int* qpreds   = (const int*)d_in[7];
    float* out = (float*)d_out;

    char* ws = (char*)d_ws;
    unsigned char* code = (unsigned char*)ws;               // 131072 B
    int* cnt            = (int*)(ws + 131072);              // 20 ints
    int* accCnt         = (int*)(ws + 131072 + 80);         // 1 int
    float* partial      = (float*)(ws + 131168);            // D*CHUNKS*20 floats
    float* S            = (float*)(ws + 131168 + D_DIM * CHUNKS * NC2 * 4);

    k_init<<<1, 64, 0, stream>>>(cnt, accCnt);
    k_code<<<256, 256, 0, stream>>>(qpreds, qlabels, code, cnt);
    k_reduce<<<dim3(CHUNKS, D_DIM), 256, 0, stream>>>(posq, negq, code, partial);
    k_finalize<<<10, 256, 0, stream>>>(partial, S);
    k_loss<<<B_N, 128, 0, stream>>>(q, preds, S, cnt, out, accCnt);
    k_acc<<<1, 1, 0, stream>>>(accCnt, out);
}